// Round 2
// baseline (527.594 us; speedup 1.0000x reference)
//
#include <hip/hip_runtime.h>
#include <hip/hip_bf16.h>

typedef __attribute__((ext_vector_type(8))) short bf16x8;
typedef __attribute__((ext_vector_type(4))) float f32x4;

#define SCALE_Q 0.18033688011112042f  // (1/sqrt(64)) * log2(e)

__device__ __forceinline__ unsigned short f2bf(float x) {
    union { float f; unsigned int u; } v; v.f = x;
    unsigned int u = v.u + 0x7fffu + ((v.u >> 16) & 1u);
    return (unsigned short)(u >> 16);
}

// ---------------- convert fp32 -> bf16 (vectorized, grid-stride) ----------------
__global__ __launch_bounds__(256) void k_cvt_bf16(const float* __restrict__ in,
                                                  unsigned short* __restrict__ out, int n8) {
    for (int i = blockIdx.x * blockDim.x + threadIdx.x; i < n8; i += gridDim.x * blockDim.x) {
        const float4* p = (const float4*)(in + (size_t)i * 8);
        float4 a = p[0], b = p[1];
        union { bf16x8 v; unsigned short s[8]; } r;
        r.s[0] = f2bf(a.x); r.s[1] = f2bf(a.y); r.s[2] = f2bf(a.z); r.s[3] = f2bf(a.w);
        r.s[4] = f2bf(b.x); r.s[5] = f2bf(b.y); r.s[6] = f2bf(b.z); r.s[7] = f2bf(b.w);
        *(bf16x8*)(out + (size_t)i * 8) = r.v;
    }
}

// ------------- transpose + convert: W[K][N] fp32 -> Wt[N][K] bf16 -------------
__global__ __launch_bounds__(256) void k_transcvt(const float* __restrict__ W,
                                                  unsigned short* __restrict__ Wt,
                                                  int K, int N, int ktiles) {
    __shared__ unsigned short T[32][33];
    const int bk = blockIdx.x % ktiles;
    const int bn = blockIdx.x / ktiles;
    const int t = threadIdx.x;
    const int r = t >> 3;
    const int c4 = (t & 7) << 2;
    float4 v = *(const float4*)(W + (size_t)(bk * 32 + r) * N + bn * 32 + c4);
    T[c4 + 0][r] = f2bf(v.x); T[c4 + 1][r] = f2bf(v.y);
    T[c4 + 2][r] = f2bf(v.z); T[c4 + 3][r] = f2bf(v.w);
    __syncthreads();
    ushort4 o; o.x = T[r][c4]; o.y = T[r][c4 + 1]; o.z = T[r][c4 + 2]; o.w = T[r][c4 + 3];
    *(ushort4*)(Wt + (size_t)(bn * 32 + r) * K + bk * 32 + c4) = o;
}

// ---------------- bf16 MFMA GEMM, 128x128 tile, BK=32, double-buffered ----------------
// A: [M][Kd] bf16 row-major.  Bt: [N][Kd] bf16 (i.e. B transposed).
// EPI=0: qkv epilogue (bias + scatter into Q / K / V^T, Q pre-scaled)
// EPI=1: fp32 out epilogue (bias + store)
#define BM 128
#define BN 128
#define BK 32

template <int EPI>
__global__ __launch_bounds__(256) void k_gemm(
    const unsigned short* __restrict__ A, const unsigned short* __restrict__ Bt,
    const float* __restrict__ bias,
    unsigned short* __restrict__ qo, unsigned short* __restrict__ ko,
    unsigned short* __restrict__ vo, float* __restrict__ fo,
    int ntn, int Kd) {
    __shared__ __align__(16) unsigned short As[2][BM * BK];
    __shared__ __align__(16) unsigned short Bs[2][BN * BK];

    const int tid = threadIdx.x, lane = tid & 63, wv = tid >> 6;
    const int nt = blockIdx.x % ntn, mt = blockIdx.x / ntn;
    const int m0 = mt * BM, n0 = nt * BN;
    const int wr = wv >> 1, wc = wv & 1;
    const int lr = lane & 15, lg = lane >> 4;

    f32x4 acc[4][4];
#pragma unroll
    for (int i = 0; i < 4; ++i)
#pragma unroll
        for (int j = 0; j < 4; ++j) acc[i][j] = (f32x4)0.f;

    const int NT = Kd >> 5;
    const int sr = wv * 16 + (lane >> 2);  // staging row within 64-row half
    const int sc = (lane & 3) * 8;         // staging k offset

    auto stage = [&](int t, int buf) {
        const int k0 = t * BK;
#pragma unroll
        for (int p = 0; p < 2; ++p) {
            const unsigned short* ga = A + (size_t)(m0 + p * 64 + sr) * Kd + k0 + sc;
            __builtin_amdgcn_global_load_lds(
                (const __attribute__((address_space(1))) void*)ga,
                (__attribute__((address_space(3))) void*)&As[buf][(p * 64 + wv * 16) * 32],
                16, 0, 0);
        }
#pragma unroll
        for (int p = 0; p < 2; ++p) {
            const unsigned short* gb = Bt + (size_t)(n0 + p * 64 + sr) * Kd + k0 + sc;
            __builtin_amdgcn_global_load_lds(
                (const __attribute__((address_space(1))) void*)gb,
                (__attribute__((address_space(3))) void*)&Bs[buf][(p * 64 + wv * 16) * 32],
                16, 0, 0);
        }
    };

    stage(0, 0);
    int cur = 0;
    for (int t = 0; t < NT; ++t) {
        __syncthreads();  // drains vmcnt (gload_lds of tile t) + lgkmcnt
        if (t + 1 < NT) stage(t + 1, cur ^ 1);
        bf16x8 af[4], bf[4];
#pragma unroll
        for (int i = 0; i < 4; ++i)
            af[i] = *(const bf16x8*)&As[cur][(wr * 64 + i * 16 + lr) * 32 + lg * 8];
#pragma unroll
        for (int j = 0; j < 4; ++j)
            bf[j] = *(const bf16x8*)&Bs[cur][(wc * 64 + j * 16 + lr) * 32 + lg * 8];
#pragma unroll
        for (int i = 0; i < 4; ++i)
#pragma unroll
            for (int j = 0; j < 4; ++j)
                acc[i][j] = __builtin_amdgcn_mfma_f32_16x16x32_bf16(af[i], bf[j], acc[i][j], 0, 0, 0);
        cur ^= 1;
    }

    // epilogue: C/D layout col = lane&15, row = (lane>>4)*4 + reg
#pragma unroll
    for (int i = 0; i < 4; ++i) {
#pragma unroll
        for (int j = 0; j < 4; ++j) {
            const int colg = n0 + wc * 64 + j * 16 + lr;
            const float bv = bias[colg];
#pragma unroll
            for (int r = 0; r < 4; ++r) {
                const int rowg = m0 + wr * 64 + i * 16 + lg * 4 + r;
                const float val = acc[i][j][r] + bv;
                if constexpr (EPI == 0) {
                    const int part = colg >> 10, d = colg & 1023;
                    const int h = d >> 6, hd = d & 63;
                    const int b = rowg >> 11, s = rowg & 2047;
                    const int bh = b * 16 + h;
                    if (part == 0)
                        qo[((size_t)(bh * 2048 + s)) * 64 + hd] = f2bf(val * SCALE_Q);
                    else if (part == 1)
                        ko[((size_t)(bh * 2048 + s)) * 64 + hd] = f2bf(val);
                    else
                        vo[((size_t)(bh * 64 + hd)) * 2048 + s] = f2bf(val);
                } else {
                    fo[(size_t)rowg * (ntn * 128) + colg] = val;
                }
            }
        }
    }
}

// ---------------- flash attention: 4 waves x 32 q-rows, KV tiles of 32 ----------------
// Q: [bh][s][hd] bf16 (prescaled by 1/sqrt(hd)*log2e), K: [bh][s][hd], Vt: [bh][hd][s]
// O: [b][s][h*64+hd] bf16
__global__ __launch_bounds__(256) void k_attn(
    const unsigned short* __restrict__ Q, const unsigned short* __restrict__ K,
    const unsigned short* __restrict__ Vt, unsigned short* __restrict__ O,
    const int* __restrict__ causal_p) {
    __shared__ __align__(16) unsigned short P[4][32 * 32];
    const int tid = threadIdx.x, lane = tid & 63, wv = tid >> 6;
    const int bh = blockIdx.x >> 4, qb = blockIdx.x & 15;
    const int q0 = qb * 128 + wv * 32;
    const int lr = lane & 15, lg = lane >> 4;
    const int causal = *causal_p;

    const unsigned short* Qp = Q + ((size_t)bh * 2048 + q0) * 64;
    const unsigned short* Kp = K + (size_t)bh * 2048 * 64;
    const unsigned short* Vp = Vt + (size_t)bh * 64 * 2048;

    bf16x8 aq[2][2];
#pragma unroll
    for (int mi = 0; mi < 2; ++mi)
#pragma unroll
        for (int h = 0; h < 2; ++h)
            aq[mi][h] = *(const bf16x8*)(Qp + (mi * 16 + lr) * 64 + h * 32 + lg * 8);

    f32x4 accO[2][4];
    float mrun[2][4], lrun[2][4];
#pragma unroll
    for (int mi = 0; mi < 2; ++mi) {
#pragma unroll
        for (int dt = 0; dt < 4; ++dt) accO[mi][dt] = (f32x4)0.f;
#pragma unroll
        for (int r = 0; r < 4; ++r) { mrun[mi][r] = -__builtin_inff(); lrun[mi][r] = 0.f; }
    }

    const int kv_end = causal ? (q0 + 32) : 2048;
    for (int kv0 = 0; kv0 < kv_end; kv0 += 32) {
        // ---- scores: S = (Q*scale) K^T  (already in log2 domain) ----
        f32x4 sc[2][2];
#pragma unroll
        for (int c = 0; c < 2; ++c) {
            const unsigned short* kp = Kp + (size_t)(kv0 + c * 16 + lr) * 64 + lg * 8;
            bf16x8 bk0 = *(const bf16x8*)kp;
            bf16x8 bk1 = *(const bf16x8*)(kp + 32);
#pragma unroll
            for (int mi = 0; mi < 2; ++mi) {
                f32x4 s = (f32x4)0.f;
                s = __builtin_amdgcn_mfma_f32_16x16x32_bf16(aq[mi][0], bk0, s, 0, 0, 0);
                s = __builtin_amdgcn_mfma_f32_16x16x32_bf16(aq[mi][1], bk1, s, 0, 0, 0);
                sc[mi][c] = s;
            }
        }
        if (causal && kv0 + 31 > q0) {
#pragma unroll
            for (int mi = 0; mi < 2; ++mi)
#pragma unroll
                for (int c = 0; c < 2; ++c) {
                    const int col = kv0 + c * 16 + lr;
#pragma unroll
                    for (int r = 0; r < 4; ++r) {
                        const int row = q0 + mi * 16 + lg * 4 + r;
                        if (col > row) sc[mi][c][r] = -__builtin_inff();
                    }
                }
        }
        // ---- online softmax (wave-parallel, 16-lane groups own 4 q-rows) ----
#pragma unroll
        for (int mi = 0; mi < 2; ++mi) {
            float corr[4];
#pragma unroll
            for (int r = 0; r < 4; ++r) {
                float tm = fmaxf(sc[mi][0][r], sc[mi][1][r]);
                tm = fmaxf(tm, __shfl_xor(tm, 1));
                tm = fmaxf(tm, __shfl_xor(tm, 2));
                tm = fmaxf(tm, __shfl_xor(tm, 4));
                tm = fmaxf(tm, __shfl_xor(tm, 8));
                const float mnew = fmaxf(mrun[mi][r], tm);
                corr[r] = exp2f(mrun[mi][r] - mnew);
                mrun[mi][r] = mnew;
                const float p0 = exp2f(sc[mi][0][r] - mnew);
                const float p1 = exp2f(sc[mi][1][r] - mnew);
                sc[mi][0][r] = p0; sc[mi][1][r] = p1;
                float rs = p0 + p1;
                rs += __shfl_xor(rs, 1);
                rs += __shfl_xor(rs, 2);
                rs += __shfl_xor(rs, 4);
                rs += __shfl_xor(rs, 8);
                lrun[mi][r] = lrun[mi][r] * corr[r] + rs;
            }
#pragma unroll
            for (int dt = 0; dt < 4; ++dt)
#pragma unroll
                for (int r = 0; r < 4; ++r) accO[mi][dt][r] *= corr[r];
            // P: C-layout -> LDS [qlocal][kvlocal] bf16
#pragma unroll
            for (int c = 0; c < 2; ++c)
#pragma unroll
                for (int r = 0; r < 4; ++r)
                    P[wv][(mi * 16 + lg * 4 + r) * 32 + c * 16 + lr] = f2bf(sc[mi][c][r]);
        }
        // ---- PV: A-frag from LDS, B-frag contiguous from V^T ----
        bf16x8 pa[2];
#pragma unroll
        for (int mi = 0; mi < 2; ++mi)
            pa[mi] = *(const bf16x8*)&P[wv][(mi * 16 + lr) * 32 + lg * 8];
#pragma unroll
        for (int dt = 0; dt < 4; ++dt) {
            bf16x8 bvv = *(const bf16x8*)(Vp + (size_t)(dt * 16 + lr) * 2048 + kv0 + lg * 8);
#pragma unroll
            for (int mi = 0; mi < 2; ++mi)
                accO[mi][dt] = __builtin_amdgcn_mfma_f32_16x16x32_bf16(pa[mi], bvv, accO[mi][dt], 0, 0, 0);
        }
    }

    // ---- epilogue: O[b][q][h*64+d] = accO / l ----
    const int b = bh >> 4, h = bh & 15;
#pragma unroll
    for (int mi = 0; mi < 2; ++mi)
#pragma unroll
        for (int r = 0; r < 4; ++r) {
            const int q = q0 + mi * 16 + lg * 4 + r;
            const float inv = 1.0f / lrun[mi][r];
            const size_t base = ((size_t)(b * 2048 + q)) * 1024 + h * 64;
#pragma unroll
            for (int dt = 0; dt < 4; ++dt)
                O[base + dt * 16 + lr] = f2bf(accO[mi][dt][r] * inv);
        }
}

extern "C" void kernel_launch(void* const* d_in, const int* in_sizes, int n_in,
                              void* d_out, int out_size, void* d_ws, size_t ws_size,
                              hipStream_t stream) {
    const float* x = (const float*)d_in[0];
    const float* Wqkv = (const float*)d_in[1];
    const float* bqkv = (const float*)d_in[2];
    const float* Wout = (const float*)d_in[3];
    const float* bout = (const float*)d_in[4];
    const int* causal = (const int*)d_in[5];
    float* out = (float*)d_out;

    char* ws = (char*)d_ws;
    unsigned short* xb  = (unsigned short*)(ws);              // 16.78 MB  x bf16 [8192][1024]
    unsigned short* wqt = (unsigned short*)(ws + 16777216);   // 6.29 MB   Wqkv^T bf16 [3072][1024]
    unsigned short* wot = (unsigned short*)(ws + 23068672);   // 2.10 MB   Wout^T bf16 [1024][1024]
    unsigned short* Qb  = (unsigned short*)(ws + 25165824);   // 16.78 MB  [64][2048][64]
    unsigned short* Kb  = (unsigned short*)(ws + 41943040);   // 16.78 MB
    unsigned short* Vtb = (unsigned short*)(ws + 58720256);   // 16.78 MB  [64][64][2048]
    unsigned short* Ob  = xb;                                 // alias: xb dead after QKV GEMM

    k_cvt_bf16<<<2048, 256, 0, stream>>>(x, xb, (8192 * 1024) / 8);
    k_transcvt<<<(1024 / 32) * (3072 / 32), 256, 0, stream>>>(Wqkv, wqt, 1024, 3072, 32);
    k_transcvt<<<(1024 / 32) * (1024 / 32), 256, 0, stream>>>(Wout, wot, 1024, 1024, 32);
    k_gemm<0><<<64 * 24, 256, 0, stream>>>(xb, wqt, bqkv, Qb, Kb, Vtb, nullptr, 24, 1024);
    k_attn<<<16 * 64, 256, 0, stream>>>(Qb, Kb, Vtb, Ob, causal);
    k_gemm<1><<<64 * 8, 256, 0, stream>>>(Ob, wot, bout, nullptr, nullptr, nullptr, out, 8, 1024);
}

// Round 5
// 446.893 us; speedup vs baseline: 1.1806x; 1.1806x over previous
//
#include <hip/hip_runtime.h>
#include <hip/hip_bf16.h>

typedef __attribute__((ext_vector_type(8))) short bf16x8;
typedef __attribute__((ext_vector_type(4))) float f32x4;

#define SCALE_Q 0.18033688011112042f  // (1/sqrt(64)) * log2(e)

__device__ __forceinline__ unsigned short f2bf(float x) {
    union { float f; unsigned int u; } v; v.f = x;
    unsigned int u = v.u + 0x7fffu + ((v.u >> 16) & 1u);
    return (unsigned short)(u >> 16);
}

// ---------------- convert fp32 -> bf16 (vectorized, grid-stride) ----------------
__global__ __launch_bounds__(256) void k_cvt_bf16(const float* __restrict__ in,
                                                  unsigned short* __restrict__ out, int n8) {
    for (int i = blockIdx.x * blockDim.x + threadIdx.x; i < n8; i += gridDim.x * blockDim.x) {
        const float4* p = (const float4*)(in + (size_t)i * 8);
        float4 a = p[0], b = p[1];
        union { bf16x8 v; unsigned short s[8]; } r;
        r.s[0] = f2bf(a.x); r.s[1] = f2bf(a.y); r.s[2] = f2bf(a.z); r.s[3] = f2bf(a.w);
        r.s[4] = f2bf(b.x); r.s[5] = f2bf(b.y); r.s[6] = f2bf(b.z); r.s[7] = f2bf(b.w);
        *(bf16x8*)(out + (size_t)i * 8) = r.v;
    }
}

// ------------- transpose + convert: W[K][N] fp32 -> Wt[N][K] bf16 -------------
__global__ __launch_bounds__(256) void k_transcvt(const float* __restrict__ W,
                                                  unsigned short* __restrict__ Wt,
                                                  int K, int N, int ktiles) {
    __shared__ unsigned short T[32][33];
    const int bk = blockIdx.x % ktiles;
    const int bn = blockIdx.x / ktiles;
    const int t = threadIdx.x;
    const int r = t >> 3;
    const int c4 = (t & 7) << 2;
    float4 v = *(const float4*)(W + (size_t)(bk * 32 + r) * N + bn * 32 + c4);
    T[c4 + 0][r] = f2bf(v.x); T[c4 + 1][r] = f2bf(v.y);
    T[c4 + 2][r] = f2bf(v.z); T[c4 + 3][r] = f2bf(v.w);
    __syncthreads();
    ushort4 o; o.x = T[r][c4]; o.y = T[r][c4 + 1]; o.z = T[r][c4 + 2]; o.w = T[r][c4 + 3];
    *(ushort4*)(Wt + (size_t)(bn * 32 + r) * K + bk * 32 + c4) = o;
}

// ---------------- bf16 MFMA GEMM, 128x128 tile, BK=32, double-buffered ----------------
#define BM 128
#define BN 128
#define BK 32

template <int EPI>
__global__ __launch_bounds__(256) void k_gemm(
    const unsigned short* __restrict__ A, const unsigned short* __restrict__ Bt,
    const float* __restrict__ bias,
    unsigned short* __restrict__ qo, unsigned short* __restrict__ ko,
    unsigned short* __restrict__ vo, float* __restrict__ fo,
    int ntn, int Kd) {
    __shared__ __align__(16) unsigned short As[2][BM * BK];
    __shared__ __align__(16) unsigned short Bs[2][BN * BK];

    const int tid = threadIdx.x, lane = tid & 63, wv = tid >> 6;
    const int nt = blockIdx.x % ntn, mt = blockIdx.x / ntn;
    const int m0 = mt * BM, n0 = nt * BN;
    const int wr = wv >> 1, wc = wv & 1;
    const int lr = lane & 15, lg = lane >> 4;

    f32x4 acc[4][4];
#pragma unroll
    for (int i = 0; i < 4; ++i)
#pragma unroll
        for (int j = 0; j < 4; ++j) acc[i][j] = (f32x4)0.f;

    const int NT = Kd >> 5;
    const int sr = wv * 16 + (lane >> 2);
    const int sc = (lane & 3) * 8;

    auto stage = [&](int t, int buf) {
        const int k0 = t * BK;
#pragma unroll
        for (int p = 0; p < 2; ++p) {
            const unsigned short* ga = A + (size_t)(m0 + p * 64 + sr) * Kd + k0 + sc;
            __builtin_amdgcn_global_load_lds(
                (const __attribute__((address_space(1))) void*)ga,
                (__attribute__((address_space(3))) void*)&As[buf][(p * 64 + wv * 16) * 32],
                16, 0, 0);
        }
#pragma unroll
        for (int p = 0; p < 2; ++p) {
            const unsigned short* gb = Bt + (size_t)(n0 + p * 64 + sr) * Kd + k0 + sc;
            __builtin_amdgcn_global_load_lds(
                (const __attribute__((address_space(1))) void*)gb,
                (__attribute__((address_space(3))) void*)&Bs[buf][(p * 64 + wv * 16) * 32],
                16, 0, 0);
        }
    };

    stage(0, 0);
    int cur = 0;
    for (int t = 0; t < NT; ++t) {
        __syncthreads();
        if (t + 1 < NT) stage(t + 1, cur ^ 1);
        bf16x8 af[4], bf[4];
#pragma unroll
        for (int i = 0; i < 4; ++i)
            af[i] = *(const bf16x8*)&As[cur][(wr * 64 + i * 16 + lr) * 32 + lg * 8];
#pragma unroll
        for (int j = 0; j < 4; ++j)
            bf[j] = *(const bf16x8*)&Bs[cur][(wc * 64 + j * 16 + lr) * 32 + lg * 8];
#pragma unroll
        for (int i = 0; i < 4; ++i)
#pragma unroll
            for (int j = 0; j < 4; ++j)
                acc[i][j] = __builtin_amdgcn_mfma_f32_16x16x32_bf16(af[i], bf[j], acc[i][j], 0, 0, 0);
        cur ^= 1;
    }

#pragma unroll
    for (int i = 0; i < 4; ++i) {
#pragma unroll
        for (int j = 0; j < 4; ++j) {
            const int colg = n0 + wc * 64 + j * 16 + lr;
            const float bv = bias[colg];
#pragma unroll
            for (int r = 0; r < 4; ++r) {
                const int rowg = m0 + wr * 64 + i * 16 + lg * 4 + r;
                const float val = acc[i][j][r] + bv;
                if constexpr (EPI == 0) {
                    const int part = colg >> 10, d = colg & 1023;
                    const int h = d >> 6, hd = d & 63;
                    const int b = rowg >> 11, s = rowg & 2047;
                    const int bh = b * 16 + h;
                    if (part == 0)
                        qo[((size_t)(bh * 2048 + s)) * 64 + hd] = f2bf(val * SCALE_Q);
                    else if (part == 1)
                        ko[((size_t)(bh * 2048 + s)) * 64 + hd] = f2bf(val);
                    else
                        vo[((size_t)(bh * 64 + hd)) * 2048 + s] = f2bf(val);
                } else {
                    fo[(size_t)rowg * (ntn * 128) + colg] = val;
                }
            }
        }
    }
}

// ---------------- flash attention, causal-balanced pair tiles ----------------
// Each wave owns TWO 16-row q-tiles: A at q0A=16*i (short causal range) and
// B at q0B=2048-16*(i+1) (long range). Work per pair = endA+endB = 2064 rows
// = constant -> balanced. K double-buffered in regs; V issued at trip top.
// Q prescaled by 1/sqrt(hd)*log2e; K: [bh][s][64]; Vt: [bh][64][s].
#define PS 40  // P row stride in shorts (80B: 16B-aligned, non-pow2 banks)

__global__ __launch_bounds__(256) void k_attn(
    const unsigned short* __restrict__ Q, const unsigned short* __restrict__ K,
    const unsigned short* __restrict__ Vt, unsigned short* __restrict__ O,
    const int* __restrict__ causal_p) {
    __shared__ __align__(16) unsigned short P[4][32 * PS];
    const int tid = threadIdx.x, lane = tid & 63, wv = tid >> 6;
    const int bh = blockIdx.x >> 4;
    const int pi = ((blockIdx.x & 15) << 2) + wv;  // pair index 0..63
    const int lr = lane & 15, lg = lane >> 4;
    const int causal = *causal_p;

    const int q0A = pi * 16;
    const int q0B = 2048 - 16 - q0A;
    const int endA = causal ? (q0A + 16) : 2048;
    const int endB = causal ? (q0B + 16) : 2048;  // endB >= endA always

    const unsigned short* Kp = K + (size_t)bh * 2048 * 64;
    const unsigned short* Vp = Vt + (size_t)bh * 64 * 2048;

    bf16x8 aA0, aA1, aB0, aB1;
    {
        const unsigned short* qa = Q + ((size_t)bh * 2048 + q0A + lr) * 64 + lg * 8;
        aA0 = *(const bf16x8*)qa; aA1 = *(const bf16x8*)(qa + 32);
        const unsigned short* qb = Q + ((size_t)bh * 2048 + q0B + lr) * 64 + lg * 8;
        aB0 = *(const bf16x8*)qb; aB1 = *(const bf16x8*)(qb + 32);
    }

    f32x4 accO[2][4];
    float mrun[2][4], lrun[2][4];
#pragma unroll
    for (int t = 0; t < 2; ++t) {
#pragma unroll
        for (int dt = 0; dt < 4; ++dt) accO[t][dt] = (f32x4)0.f;
#pragma unroll
        for (int r = 0; r < 4; ++r) { mrun[t][r] = -__builtin_inff(); lrun[t][r] = 0.f; }
    }

    auto loadK = [&](int kv, bf16x8& c00, bf16x8& c01, bf16x8& c10, bf16x8& c11) {
        const unsigned short* kp = Kp + (size_t)(kv + lr) * 64 + lg * 8;
        c00 = *(const bf16x8*)kp;          c01 = *(const bf16x8*)(kp + 32);
        c10 = *(const bf16x8*)(kp + 1024); c11 = *(const bf16x8*)(kp + 1024 + 32);
    };

    // one q-tile step: QK^T -> online softmax -> P via LDS -> PV
    auto tile_step = [&](int t, int q0t, const bf16x8& a0, const bf16x8& a1, int kv0,
                         const bf16x8& k00, const bf16x8& k01,
                         const bf16x8& k10, const bf16x8& k11, const bf16x8* vf) {
        f32x4 s0 = (f32x4)0.f, s1 = (f32x4)0.f;
        s0 = __builtin_amdgcn_mfma_f32_16x16x32_bf16(a0, k00, s0, 0, 0, 0);
        s0 = __builtin_amdgcn_mfma_f32_16x16x32_bf16(a1, k01, s0, 0, 0, 0);
        s1 = __builtin_amdgcn_mfma_f32_16x16x32_bf16(a0, k10, s1, 0, 0, 0);
        s1 = __builtin_amdgcn_mfma_f32_16x16x32_bf16(a1, k11, s1, 0, 0, 0);
        if (causal && kv0 + 31 > q0t) {
#pragma unroll
            for (int r = 0; r < 4; ++r) {
                const int row = q0t + lg * 4 + r;
                if (kv0 + lr > row) s0[r] = -__builtin_inff();
                if (kv0 + 16 + lr > row) s1[r] = -__builtin_inff();
            }
        }
        float corr[4];
#pragma unroll
        for (int r = 0; r < 4; ++r) {
            float tm = fmaxf(s0[r], s1[r]);
            tm = fmaxf(tm, __shfl_xor(tm, 1));
            tm = fmaxf(tm, __shfl_xor(tm, 2));
            tm = fmaxf(tm, __shfl_xor(tm, 4));
            tm = fmaxf(tm, __shfl_xor(tm, 8));
            const float mnew = fmaxf(mrun[t][r], tm);
            corr[r] = exp2f(mrun[t][r] - mnew);
            mrun[t][r] = mnew;
            const float p0 = exp2f(s0[r] - mnew);
            const float p1 = exp2f(s1[r] - mnew);
            s0[r] = p0; s1[r] = p1;
            float rs = p0 + p1;
            rs += __shfl_xor(rs, 1);
            rs += __shfl_xor(rs, 2);
            rs += __shfl_xor(rs, 4);
            rs += __shfl_xor(rs, 8);
            lrun[t][r] = lrun[t][r] * corr[r] + rs;
        }
#pragma unroll
        for (int dt = 0; dt < 4; ++dt)
#pragma unroll
            for (int r = 0; r < 4; ++r) accO[t][dt][r] *= corr[r];
#pragma unroll
        for (int r = 0; r < 4; ++r) {
            P[wv][(t * 16 + lg * 4 + r) * PS + lr] = f2bf(s0[r]);
            P[wv][(t * 16 + lg * 4 + r) * PS + 16 + lr] = f2bf(s1[r]);
        }
        bf16x8 pa = *(const bf16x8*)&P[wv][(t * 16 + lr) * PS + lg * 8];
#pragma unroll
        for (int dt = 0; dt < 4; ++dt)
            accO[t][dt] = __builtin_amdgcn_mfma_f32_16x16x32_bf16(pa, vf[dt], accO[t][dt], 0, 0, 0);
    };

    auto body = [&](int kv0, const bf16x8& k00, const bf16x8& k01,
                    const bf16x8& k10, const bf16x8& k11) {
        bf16x8 vf[4];
#pragma unroll
        for (int dt = 0; dt < 4; ++dt)
            vf[dt] = *(const bf16x8*)(Vp + (size_t)(dt * 16 + lr) * 2048 + kv0 + lg * 8);
        if (kv0 < endA) tile_step(0, q0A, aA0, aA1, kv0, k00, k01, k10, k11, vf);
        tile_step(1, q0B, aB0, aB1, kv0, k00, k01, k10, k11, vf);
    };

    bf16x8 xk00, xk01, xk10, xk11;  // buffer X
    bf16x8 yk00, yk01, yk10, yk11;  // buffer Y
    loadK(0, xk00, xk01, xk10, xk11);
    int kv0 = 0;
    for (;;) {
        if (kv0 + 32 < endB) loadK(kv0 + 32, yk00, yk01, yk10, yk11);
        body(kv0, xk00, xk01, xk10, xk11);
        kv0 += 32;
        if (kv0 >= endB) break;
        if (kv0 + 32 < endB) loadK(kv0 + 32, xk00, xk01, xk10, xk11);
        body(kv0, yk00, yk01, yk10, yk11);
        kv0 += 32;
        if (kv0 >= endB) break;
    }

    // epilogue
    const int b = bh >> 4, h = bh & 15;
#pragma unroll
    for (int t = 0; t < 2; ++t) {
        const int q0t = t ? q0B : q0A;
#pragma unroll
        for (int r = 0; r < 4; ++r) {
            const int q = q0t + lg * 4 + r;
            const float inv = 1.0f / lrun[t][r];
            const size_t base = ((size_t)(b * 2048 + q)) * 1024 + h * 64;
#pragma unroll
            for (int dt = 0; dt < 4; ++dt)
                O[base + dt * 16 + lr] = f2bf(accO[t][dt][r] * inv);
        }
    }
}

extern "C" void kernel_launch(void* const* d_in, const int* in_sizes, int n_in,
                              void* d_out, int out_size, void* d_ws, size_t ws_size,
                              hipStream_t stream) {
    const float* x = (const float*)d_in[0];
    const float* Wqkv = (const float*)d_in[1];
    const float* bqkv = (const float*)d_in[2];
    const float* Wout = (const float*)d_in[3];
    const float* bout = (const float*)d_in[4];
    const int* causal = (const int*)d_in[5];
    float* out = (float*)d_out;

    char* ws = (char*)d_ws;
    unsigned short* xb  = (unsigned short*)(ws);              // 16.78 MB  x bf16 [8192][1024]
    unsigned short* wqt = (unsigned short*)(ws + 16777216);   // 6.29 MB   Wqkv^T bf16 [3072][1024]
    unsigned short* wot = (unsigned short*)(ws + 23068672);   // 2.10 MB   Wout^T bf16 [1024][1024]
    unsigned short* Qb  = (unsigned short*)(ws + 25165824);   // 16.78 MB  [64][2048][64]
    unsigned short* Kb  = (unsigned short*)(ws + 41943040);   // 16.78 MB
    unsigned short* Vtb = (unsigned short*)(ws + 58720256);   // 16.78 MB  [64][64][2048]
    unsigned short* Ob  = xb;                                 // alias: xb dead after QKV GEMM

    k_cvt_bf16<<<2048, 256, 0, stream>>>(x, xb, (8192 * 1024) / 8);
    k_transcvt<<<(1024 / 32) * (3072 / 32), 256, 0, stream>>>(Wqkv, wqt, 1024, 3072, 32);
    k_transcvt<<<(1024 / 32) * (1024 / 32), 256, 0, stream>>>(Wout, wot, 1024, 1024, 32);
    k_gemm<0><<<64 * 24, 256, 0, stream>>>(xb, wqt, bqkv, Qb, Kb, Vtb, nullptr, 24, 1024);
    k_attn<<<64 * 16, 256, 0, stream>>>(Qb, Kb, Vtb, Ob, causal);
    k_gemm<1><<<64 * 8, 256, 0, stream>>>(Ob, wot, bout, nullptr, nullptr, nullptr, out, 8, 1024);
}

// Round 6
// 443.455 us; speedup vs baseline: 1.1897x; 1.0078x over previous
//
#include <hip/hip_runtime.h>
#include <hip/hip_bf16.h>

typedef __attribute__((ext_vector_type(8))) short bf16x8;
typedef __attribute__((ext_vector_type(4))) float f32x4;

#define SCALE_Q 0.18033688011112042f  // (1/sqrt(64)) * log2(e)

__device__ __forceinline__ unsigned short f2bf(float x) {
    union { float f; unsigned int u; } v; v.f = x;
    unsigned int u = v.u + 0x7fffu + ((v.u >> 16) & 1u);
    return (unsigned short)(u >> 16);
}

// ---------------- convert fp32 -> bf16 (vectorized, grid-stride) ----------------
__global__ __launch_bounds__(256) void k_cvt_bf16(const float* __restrict__ in,
                                                  unsigned short* __restrict__ out, int n8) {
    for (int i = blockIdx.x * blockDim.x + threadIdx.x; i < n8; i += gridDim.x * blockDim.x) {
        const float4* p = (const float4*)(in + (size_t)i * 8);
        float4 a = p[0], b = p[1];
        union { bf16x8 v; unsigned short s[8]; } r;
        r.s[0] = f2bf(a.x); r.s[1] = f2bf(a.y); r.s[2] = f2bf(a.z); r.s[3] = f2bf(a.w);
        r.s[4] = f2bf(b.x); r.s[5] = f2bf(b.y); r.s[6] = f2bf(b.z); r.s[7] = f2bf(b.w);
        *(bf16x8*)(out + (size_t)i * 8) = r.v;
    }
}

// ------------- transpose + convert: W[K][N] fp32 -> Wt[N][K] bf16 -------------
__global__ __launch_bounds__(256) void k_transcvt(const float* __restrict__ W,
                                                  unsigned short* __restrict__ Wt,
                                                  int K, int N, int ktiles) {
    __shared__ unsigned short T[32][33];
    const int bk = blockIdx.x % ktiles;
    const int bn = blockIdx.x / ktiles;
    const int t = threadIdx.x;
    const int r = t >> 3;
    const int c4 = (t & 7) << 2;
    float4 v = *(const float4*)(W + (size_t)(bk * 32 + r) * N + bn * 32 + c4);
    T[c4 + 0][r] = f2bf(v.x); T[c4 + 1][r] = f2bf(v.y);
    T[c4 + 2][r] = f2bf(v.z); T[c4 + 3][r] = f2bf(v.w);
    __syncthreads();
    ushort4 o; o.x = T[r][c4]; o.y = T[r][c4 + 1]; o.z = T[r][c4 + 2]; o.w = T[r][c4 + 3];
    *(ushort4*)(Wt + (size_t)(bn * 32 + r) * K + bk * 32 + c4) = o;
}

// ---------------- bf16 MFMA GEMM, 128x128 tile, BK=32, double-buffered ----------------
#define BM 128
#define BN 128
#define BK 32

template <int EPI>
__global__ __launch_bounds__(256) void k_gemm(
    const unsigned short* __restrict__ A, const unsigned short* __restrict__ Bt,
    const float* __restrict__ bias,
    unsigned short* __restrict__ qo, unsigned short* __restrict__ ko,
    unsigned short* __restrict__ vo, float* __restrict__ fo,
    int ntn, int Kd) {
    __shared__ __align__(16) unsigned short As[2][BM * BK];
    __shared__ __align__(16) unsigned short Bs[2][BN * BK];

    const int tid = threadIdx.x, lane = tid & 63, wv = tid >> 6;
    const int nt = blockIdx.x % ntn, mt = blockIdx.x / ntn;
    const int m0 = mt * BM, n0 = nt * BN;
    const int wr = wv >> 1, wc = wv & 1;
    const int lr = lane & 15, lg = lane >> 4;

    f32x4 acc[4][4];
#pragma unroll
    for (int i = 0; i < 4; ++i)
#pragma unroll
        for (int j = 0; j < 4; ++j) acc[i][j] = (f32x4)0.f;

    const int NT = Kd >> 5;
    const int sr = wv * 16 + (lane >> 2);
    const int sc = (lane & 3) * 8;

    auto stage = [&](int t, int buf) {
        const int k0 = t * BK;
#pragma unroll
        for (int p = 0; p < 2; ++p) {
            const unsigned short* ga = A + (size_t)(m0 + p * 64 + sr) * Kd + k0 + sc;
            __builtin_amdgcn_global_load_lds(
                (const __attribute__((address_space(1))) void*)ga,
                (__attribute__((address_space(3))) void*)&As[buf][(p * 64 + wv * 16) * 32],
                16, 0, 0);
        }
#pragma unroll
        for (int p = 0; p < 2; ++p) {
            const unsigned short* gb = Bt + (size_t)(n0 + p * 64 + sr) * Kd + k0 + sc;
            __builtin_amdgcn_global_load_lds(
                (const __attribute__((address_space(1))) void*)gb,
                (__attribute__((address_space(3))) void*)&Bs[buf][(p * 64 + wv * 16) * 32],
                16, 0, 0);
        }
    };

    stage(0, 0);
    int cur = 0;
    for (int t = 0; t < NT; ++t) {
        __syncthreads();
        if (t + 1 < NT) stage(t + 1, cur ^ 1);
        bf16x8 af[4], bf[4];
#pragma unroll
        for (int i = 0; i < 4; ++i)
            af[i] = *(const bf16x8*)&As[cur][(wr * 64 + i * 16 + lr) * 32 + lg * 8];
#pragma unroll
        for (int j = 0; j < 4; ++j)
            bf[j] = *(const bf16x8*)&Bs[cur][(wc * 64 + j * 16 + lr) * 32 + lg * 8];
#pragma unroll
        for (int i = 0; i < 4; ++i)
#pragma unroll
            for (int j = 0; j < 4; ++j)
                acc[i][j] = __builtin_amdgcn_mfma_f32_16x16x32_bf16(af[i], bf[j], acc[i][j], 0, 0, 0);
        cur ^= 1;
    }

#pragma unroll
    for (int i = 0; i < 4; ++i) {
#pragma unroll
        for (int j = 0; j < 4; ++j) {
            const int colg = n0 + wc * 64 + j * 16 + lr;
            const float bv = bias[colg];
#pragma unroll
            for (int r = 0; r < 4; ++r) {
                const int rowg = m0 + wr * 64 + i * 16 + lg * 4 + r;
                const float val = acc[i][j][r] + bv;
                if constexpr (EPI == 0) {
                    const int part = colg >> 10, d = colg & 1023;
                    const int h = d >> 6, hd = d & 63;
                    const int b = rowg >> 11, s = rowg & 2047;
                    const int bh = b * 16 + h;
                    if (part == 0)
                        qo[((size_t)(bh * 2048 + s)) * 64 + hd] = f2bf(val * SCALE_Q);
                    else if (part == 1)
                        ko[((size_t)(bh * 2048 + s)) * 64 + hd] = f2bf(val);
                    else
                        vo[((size_t)(bh * 64 + hd)) * 2048 + s] = f2bf(val);
                } else {
                    fo[(size_t)rowg * (ntn * 128) + colg] = val;
                }
            }
        }
    }
}

// ---------------- flash attention v3: pair tiles, KVBLK=64, defer-max ----------------
// Wave owns q-tile A (16 rows at 16*pi) + B (mirrored). KVBLK=64: 4 col-subtiles
// per softmax pass -> half the shfl chains / rescales per kv vs KVBLK=32.
// Defer-max (THR=8, log2 domain): skip corr+rescale unless tile max grows.
// K single-buffered, prefetched after last QK^T use; V split dt{0,1}/dt{2,3}.
#define PS 72     // P row stride in shorts (144B: 16B-aligned, non-pow2 banks)
#define THR 8.0f

__global__ __launch_bounds__(256) void k_attn(
    const unsigned short* __restrict__ Q, const unsigned short* __restrict__ K,
    const unsigned short* __restrict__ Vt, unsigned short* __restrict__ O,
    const int* __restrict__ causal_p) {
    __shared__ __align__(16) unsigned short P[4][32 * PS];
    const int tid = threadIdx.x, lane = tid & 63, wv = tid >> 6;
    const int bh = blockIdx.x >> 4;
    const int pi = ((blockIdx.x & 15) << 2) + wv;  // pair index 0..63
    const int lr = lane & 15, lg = lane >> 4;
    const int causal = *causal_p;

    const int q0A = pi * 16;
    const int q0B = 2048 - 16 - q0A;
    const int endA = causal ? (q0A + 16) : 2048;
    const int endB = causal ? (q0B + 16) : 2048;  // endB >= endA

    const unsigned short* Kp = K + (size_t)bh * 2048 * 64;
    const unsigned short* Vp = Vt + (size_t)bh * 64 * 2048;

    bf16x8 aA0, aA1, aB0, aB1;
    {
        const unsigned short* qa = Q + ((size_t)bh * 2048 + q0A + lr) * 64 + lg * 8;
        aA0 = *(const bf16x8*)qa; aA1 = *(const bf16x8*)(qa + 32);
        const unsigned short* qb = Q + ((size_t)bh * 2048 + q0B + lr) * 64 + lg * 8;
        aB0 = *(const bf16x8*)qb; aB1 = *(const bf16x8*)(qb + 32);
    }

    f32x4 accO[2][4];
    float mrun[2][4], lrun[2][4];
#pragma unroll
    for (int t = 0; t < 2; ++t) {
#pragma unroll
        for (int dt = 0; dt < 4; ++dt) accO[t][dt] = (f32x4)0.f;
#pragma unroll
        for (int r = 0; r < 4; ++r) { mrun[t][r] = -__builtin_inff(); lrun[t][r] = 0.f; }
    }

    bf16x8 kb[8];  // K tile: 64 kv rows (4 c-subtiles x 2 k-halves)
    auto loadK = [&](int kv) {
#pragma unroll
        for (int c = 0; c < 4; ++c) {
            const unsigned short* kp = Kp + (size_t)(kv + c * 16 + lr) * 64 + lg * 8;
            kb[c * 2] = *(const bf16x8*)kp;
            kb[c * 2 + 1] = *(const bf16x8*)(kp + 32);
        }
    };

    auto qkt = [&](const bf16x8& a0, const bf16x8& a1, f32x4* s) {
        __builtin_amdgcn_s_setprio(1);
#pragma unroll
        for (int c = 0; c < 4; ++c) {
            f32x4 v = (f32x4)0.f;
            v = __builtin_amdgcn_mfma_f32_16x16x32_bf16(a0, kb[c * 2], v, 0, 0, 0);
            v = __builtin_amdgcn_mfma_f32_16x16x32_bf16(a1, kb[c * 2 + 1], v, 0, 0, 0);
            s[c] = v;
        }
        __builtin_amdgcn_s_setprio(0);
    };

    auto maskf = [&](f32x4* s, int q0t, int kv0) {
        if (causal && kv0 + 63 > q0t) {
#pragma unroll
            for (int c = 0; c < 4; ++c) {
                const int col = kv0 + c * 16 + lr;
#pragma unroll
                for (int r = 0; r < 4; ++r)
                    if (col > q0t + lg * 4 + r) s[c][r] = -__builtin_inff();
            }
        }
    };

    // online softmax with defer-max; writes P rows [t*16, t*16+16)
    auto softmax_p = [&](int t, f32x4* s) {
        float pm[4];
        bool sk = true;
#pragma unroll
        for (int r = 0; r < 4; ++r) {
            float tm = fmaxf(fmaxf(s[0][r], s[1][r]), fmaxf(s[2][r], s[3][r]));
            tm = fmaxf(tm, __shfl_xor(tm, 1));
            tm = fmaxf(tm, __shfl_xor(tm, 2));
            tm = fmaxf(tm, __shfl_xor(tm, 4));
            tm = fmaxf(tm, __shfl_xor(tm, 8));
            pm[r] = tm;
            sk = sk && (tm <= mrun[t][r] + THR);
        }
        if (!__all(sk)) {
#pragma unroll
            for (int r = 0; r < 4; ++r) {
                const float mnew = fmaxf(mrun[t][r], pm[r]);
                const float corr = exp2f(mrun[t][r] - mnew);
                mrun[t][r] = mnew;
                lrun[t][r] *= corr;
#pragma unroll
                for (int dt = 0; dt < 4; ++dt) accO[t][dt][r] *= corr;
            }
        }
#pragma unroll
        for (int r = 0; r < 4; ++r) {
            float rs = 0.f;
#pragma unroll
            for (int c = 0; c < 4; ++c) {
                const float p = exp2f(s[c][r] - mrun[t][r]);
                P[wv][(t * 16 + lg * 4 + r) * PS + c * 16 + lr] = f2bf(p);
                rs += p;
            }
            rs += __shfl_xor(rs, 1);
            rs += __shfl_xor(rs, 2);
            rs += __shfl_xor(rs, 4);
            rs += __shfl_xor(rs, 8);
            lrun[t][r] += rs;
        }
    };

    loadK(0);
    for (int kv0 = 0; kv0 < endB; kv0 += 64) {
        const bool actA = (kv0 < endA);
        // V dt{0,1} issued early: consumed ~300cy later in PV
        bf16x8 vA[4];
#pragma unroll
        for (int i = 0; i < 4; ++i) {
            const int dt = i >> 1, h = i & 1;
            vA[i] = *(const bf16x8*)(Vp + (size_t)(dt * 16 + lr) * 2048 + kv0 + h * 32 + lg * 8);
        }
        f32x4 s[4];
        if (actA) {
            qkt(aA0, aA1, s);
            maskf(s, q0A, kv0);
            softmax_p(0, s);
        }
        qkt(aB0, aB1, s);
        if (kv0 + 64 < endB) loadK(kv0 + 64);  // kb free after last QK^T issue
        maskf(s, q0B, kv0);
        softmax_p(1, s);
        bf16x8 vB[4];
#pragma unroll
        for (int i = 0; i < 4; ++i) {
            const int dt = 2 + (i >> 1), h = i & 1;
            vB[i] = *(const bf16x8*)(Vp + (size_t)(dt * 16 + lr) * 2048 + kv0 + h * 32 + lg * 8);
        }
        bf16x8 paA0, paA1, paB0, paB1;
        if (actA) {
            paA0 = *(const bf16x8*)&P[wv][lr * PS + lg * 8];
            paA1 = *(const bf16x8*)&P[wv][lr * PS + 32 + lg * 8];
        }
        paB0 = *(const bf16x8*)&P[wv][(16 + lr) * PS + lg * 8];
        paB1 = *(const bf16x8*)&P[wv][(16 + lr) * PS + 32 + lg * 8];
        __builtin_amdgcn_s_setprio(1);
#pragma unroll
        for (int dt = 0; dt < 2; ++dt) {
            if (actA) {
                accO[0][dt] = __builtin_amdgcn_mfma_f32_16x16x32_bf16(paA0, vA[dt * 2], accO[0][dt], 0, 0, 0);
                accO[0][dt] = __builtin_amdgcn_mfma_f32_16x16x32_bf16(paA1, vA[dt * 2 + 1], accO[0][dt], 0, 0, 0);
            }
            accO[1][dt] = __builtin_amdgcn_mfma_f32_16x16x32_bf16(paB0, vA[dt * 2], accO[1][dt], 0, 0, 0);
            accO[1][dt] = __builtin_amdgcn_mfma_f32_16x16x32_bf16(paB1, vA[dt * 2 + 1], accO[1][dt], 0, 0, 0);
        }
#pragma unroll
        for (int dt = 0; dt < 2; ++dt) {
            if (actA) {
                accO[0][2 + dt] = __builtin_amdgcn_mfma_f32_16x16x32_bf16(paA0, vB[dt * 2], accO[0][2 + dt], 0, 0, 0);
                accO[0][2 + dt] = __builtin_amdgcn_mfma_f32_16x16x32_bf16(paA1, vB[dt * 2 + 1], accO[0][2 + dt], 0, 0, 0);
            }
            accO[1][2 + dt] = __builtin_amdgcn_mfma_f32_16x16x32_bf16(paB0, vB[dt * 2], accO[1][2 + dt], 0, 0, 0);
            accO[1][2 + dt] = __builtin_amdgcn_mfma_f32_16x16x32_bf16(paB1, vB[dt * 2 + 1], accO[1][2 + dt], 0, 0, 0);
        }
        __builtin_amdgcn_s_setprio(0);
    }

    // epilogue
    const int b = bh >> 4, h = bh & 15;
#pragma unroll
    for (int t = 0; t < 2; ++t) {
        const int q0t = t ? q0B : q0A;
#pragma unroll
        for (int r = 0; r < 4; ++r) {
            const int q = q0t + lg * 4 + r;
            const float inv = 1.0f / lrun[t][r];
            const size_t base = ((size_t)(b * 2048 + q)) * 1024 + h * 64;
#pragma unroll
            for (int dt = 0; dt < 4; ++dt)
                O[base + dt * 16 + lr] = f2bf(accO[t][dt][r] * inv);
        }
    }
}

extern "C" void kernel_launch(void* const* d_in, const int* in_sizes, int n_in,
                              void* d_out, int out_size, void* d_ws, size_t ws_size,
                              hipStream_t stream) {
    const float* x = (const float*)d_in[0];
    const float* Wqkv = (const float*)d_in[1];
    const float* bqkv = (const float*)d_in[2];
    const float* Wout = (const float*)d_in[3];
    const float* bout = (const float*)d_in[4];
    const int* causal = (const int*)d_in[5];
    float* out = (float*)d_out;

    char* ws = (char*)d_ws;
    unsigned short* xb  = (unsigned short*)(ws);              // 16.78 MB  x bf16 [8192][1024]
    unsigned short* wqt = (unsigned short*)(ws + 16777216);   // 6.29 MB   Wqkv^T bf16 [3072][1024]
    unsigned short* wot = (unsigned short*)(ws + 23068672);   // 2.10 MB   Wout^T bf16 [1024][1024]
    unsigned short* Qb  = (unsigned short*)(ws + 25165824);   // 16.78 MB  [64][2048][64]
    unsigned short* Kb  = (unsigned short*)(ws + 41943040);   // 16.78 MB
    unsigned short* Vtb = (unsigned short*)(ws + 58720256);   // 16.78 MB  [64][64][2048]
    unsigned short* Ob  = xb;                                 // alias: xb dead after QKV GEMM

    k_cvt_bf16<<<2048, 256, 0, stream>>>(x, xb, (8192 * 1024) / 8);
    k_transcvt<<<(1024 / 32) * (3072 / 32), 256, 0, stream>>>(Wqkv, wqt, 1024, 3072, 32);
    k_transcvt<<<(1024 / 32) * (1024 / 32), 256, 0, stream>>>(Wout, wot, 1024, 1024, 32);
    k_gemm<0><<<64 * 24, 256, 0, stream>>>(xb, wqt, bqkv, Qb, Kb, Vtb, nullptr, 24, 1024);
    k_attn<<<64 * 16, 256, 0, stream>>>(Qb, Kb, Vtb, Ob, causal);
    k_gemm<1><<<64 * 8, 256, 0, stream>>>(Ob, wot, bout, nullptr, nullptr, nullptr, out, 8, 1024);
}

// Round 7
// 418.949 us; speedup vs baseline: 1.2593x; 1.0585x over previous
//
#include <hip/hip_runtime.h>
#include <hip/hip_bf16.h>

typedef __attribute__((ext_vector_type(8))) short bf16x8;
typedef __attribute__((ext_vector_type(4))) float f32x4;

#define SCALE_Q 0.18033688011112042f  // (1/sqrt(64)) * log2(e)

__device__ __forceinline__ unsigned short f2bf(float x) {
    union { float f; unsigned int u; } v; v.f = x;
    unsigned int u = v.u + 0x7fffu + ((v.u >> 16) & 1u);
    return (unsigned short)(u >> 16);
}

// XCD-aware bijective block remap (requires nwg % 8 == 0): hardware ids
// round-robin XCDs, so (bid&7)==x all land on XCD x and execute a
// CONTIGUOUS logical chunk -> co-resident blocks share L2 working set.
__device__ __forceinline__ int xcd_swz(int bid, int nwg) {
    return (bid & 7) * (nwg >> 3) + (bid >> 3);
}

// ---------------- convert fp32 -> bf16 (vectorized, grid-stride) ----------------
__global__ __launch_bounds__(256) void k_cvt_bf16(const float* __restrict__ in,
                                                  unsigned short* __restrict__ out, int n8) {
    for (int i = blockIdx.x * blockDim.x + threadIdx.x; i < n8; i += gridDim.x * blockDim.x) {
        const float4* p = (const float4*)(in + (size_t)i * 8);
        float4 a = p[0], b = p[1];
        union { bf16x8 v; unsigned short s[8]; } r;
        r.s[0] = f2bf(a.x); r.s[1] = f2bf(a.y); r.s[2] = f2bf(a.z); r.s[3] = f2bf(a.w);
        r.s[4] = f2bf(b.x); r.s[5] = f2bf(b.y); r.s[6] = f2bf(b.z); r.s[7] = f2bf(b.w);
        *(bf16x8*)(out + (size_t)i * 8) = r.v;
    }
}

// ------------- transpose + convert: W[K][N] fp32 -> Wt[N][K] bf16 -------------
__global__ __launch_bounds__(256) void k_transcvt(const float* __restrict__ W,
                                                  unsigned short* __restrict__ Wt,
                                                  int K, int N, int ktiles) {
    __shared__ unsigned short T[32][33];
    const int bk = blockIdx.x % ktiles;
    const int bn = blockIdx.x / ktiles;
    const int t = threadIdx.x;
    const int r = t >> 3;
    const int c4 = (t & 7) << 2;
    float4 v = *(const float4*)(W + (size_t)(bk * 32 + r) * N + bn * 32 + c4);
    T[c4 + 0][r] = f2bf(v.x); T[c4 + 1][r] = f2bf(v.y);
    T[c4 + 2][r] = f2bf(v.z); T[c4 + 3][r] = f2bf(v.w);
    __syncthreads();
    ushort4 o; o.x = T[r][c4]; o.y = T[r][c4 + 1]; o.z = T[r][c4 + 2]; o.w = T[r][c4 + 3];
    *(ushort4*)(Wt + (size_t)(bn * 32 + r) * K + bk * 32 + c4) = o;
}

// ---------------- bf16 MFMA GEMM, 128x128 tile, BK=32, double-buffered ----------------
#define BM 128
#define BN 128
#define BK 32

template <int EPI>
__global__ __launch_bounds__(256) void k_gemm(
    const unsigned short* __restrict__ A, const unsigned short* __restrict__ Bt,
    const float* __restrict__ bias,
    unsigned short* __restrict__ qo, unsigned short* __restrict__ ko,
    unsigned short* __restrict__ vo, float* __restrict__ fo,
    int ntn, int Kd, int nwg) {
    __shared__ __align__(16) unsigned short As[2][BM * BK];
    __shared__ __align__(16) unsigned short Bs[2][BN * BK];

    const int tid = threadIdx.x, lane = tid & 63, wv = tid >> 6;
    const int lb = xcd_swz(blockIdx.x, nwg);
    const int nt = lb % ntn, mt = lb / ntn;
    const int m0 = mt * BM, n0 = nt * BN;
    const int wr = wv >> 1, wc = wv & 1;
    const int lr = lane & 15, lg = lane >> 4;

    f32x4 acc[4][4];
#pragma unroll
    for (int i = 0; i < 4; ++i)
#pragma unroll
        for (int j = 0; j < 4; ++j) acc[i][j] = (f32x4)0.f;

    const int NT = Kd >> 5;
    const int sr = wv * 16 + (lane >> 2);
    const int sc = (lane & 3) * 8;

    auto stage = [&](int t, int buf) {
        const int k0 = t * BK;
#pragma unroll
        for (int p = 0; p < 2; ++p) {
            const unsigned short* ga = A + (size_t)(m0 + p * 64 + sr) * Kd + k0 + sc;
            __builtin_amdgcn_global_load_lds(
                (const __attribute__((address_space(1))) void*)ga,
                (__attribute__((address_space(3))) void*)&As[buf][(p * 64 + wv * 16) * 32],
                16, 0, 0);
        }
#pragma unroll
        for (int p = 0; p < 2; ++p) {
            const unsigned short* gb = Bt + (size_t)(n0 + p * 64 + sr) * Kd + k0 + sc;
            __builtin_amdgcn_global_load_lds(
                (const __attribute__((address_space(1))) void*)gb,
                (__attribute__((address_space(3))) void*)&Bs[buf][(p * 64 + wv * 16) * 32],
                16, 0, 0);
        }
    };

    stage(0, 0);
    int cur = 0;
    for (int t = 0; t < NT; ++t) {
        __syncthreads();
        if (t + 1 < NT) stage(t + 1, cur ^ 1);
        bf16x8 af[4], bf[4];
#pragma unroll
        for (int i = 0; i < 4; ++i)
            af[i] = *(const bf16x8*)&As[cur][(wr * 64 + i * 16 + lr) * 32 + lg * 8];
#pragma unroll
        for (int j = 0; j < 4; ++j)
            bf[j] = *(const bf16x8*)&Bs[cur][(wc * 64 + j * 16 + lr) * 32 + lg * 8];
#pragma unroll
        for (int i = 0; i < 4; ++i)
#pragma unroll
            for (int j = 0; j < 4; ++j)
                acc[i][j] = __builtin_amdgcn_mfma_f32_16x16x32_bf16(af[i], bf[j], acc[i][j], 0, 0, 0);
        cur ^= 1;
    }

#pragma unroll
    for (int i = 0; i < 4; ++i) {
#pragma unroll
        for (int j = 0; j < 4; ++j) {
            const int colg = n0 + wc * 64 + j * 16 + lr;
            const float bv = bias[colg];
#pragma unroll
            for (int r = 0; r < 4; ++r) {
                const int rowg = m0 + wr * 64 + i * 16 + lg * 4 + r;
                const float val = acc[i][j][r] + bv;
                if constexpr (EPI == 0) {
                    const int part = colg >> 10, d = colg & 1023;
                    const int h = d >> 6, hd = d & 63;
                    const int b = rowg >> 11, s = rowg & 2047;
                    const int bh = b * 16 + h;
                    if (part == 0)
                        qo[((size_t)(bh * 2048 + s)) * 64 + hd] = f2bf(val * SCALE_Q);
                    else if (part == 1)
                        ko[((size_t)(bh * 2048 + s)) * 64 + hd] = f2bf(val);
                    else
                        vo[((size_t)(bh * 64 + hd)) * 2048 + s] = f2bf(val);
                } else {
                    fo[(size_t)rowg * (ntn * 128) + colg] = val;
                }
            }
        }
    }
}

// ---------------- flash attention v4: pair tiles + XCD swizzle ----------------
// XCD swizzle: all 16 q-blocks of one bh land on ONE XCD -> per-XCD K/V
// working set = 8 bh x 512KB = 4MB = L2 -> K/V HBM-fetched once.
// Wave owns q-tile A (16 rows at 16*pi) + B (mirrored); KVBLK=64; defer-max.
#define PS 72     // P row stride in shorts (144B: 16B-aligned, non-pow2 banks)
#define THR 8.0f

__global__ __launch_bounds__(256) void k_attn(
    const unsigned short* __restrict__ Q, const unsigned short* __restrict__ K,
    const unsigned short* __restrict__ Vt, unsigned short* __restrict__ O,
    const int* __restrict__ causal_p) {
    __shared__ __align__(16) unsigned short P[4][32 * PS];
    const int tid = threadIdx.x, lane = tid & 63, wv = tid >> 6;
    const int lb = xcd_swz(blockIdx.x, 64 * 16);
    const int bh = lb >> 4;
    const int pi = ((lb & 15) << 2) + wv;  // pair index 0..63
    const int lr = lane & 15, lg = lane >> 4;
    const int causal = *causal_p;

    const int q0A = pi * 16;
    const int q0B = 2048 - 16 - q0A;
    const int endA = causal ? (q0A + 16) : 2048;
    const int endB = causal ? (q0B + 16) : 2048;  // endB >= endA

    const unsigned short* Kp = K + (size_t)bh * 2048 * 64;
    const unsigned short* Vp = Vt + (size_t)bh * 64 * 2048;

    bf16x8 aA0, aA1, aB0, aB1;
    {
        const unsigned short* qa = Q + ((size_t)bh * 2048 + q0A + lr) * 64 + lg * 8;
        aA0 = *(const bf16x8*)qa; aA1 = *(const bf16x8*)(qa + 32);
        const unsigned short* qb = Q + ((size_t)bh * 2048 + q0B + lr) * 64 + lg * 8;
        aB0 = *(const bf16x8*)qb; aB1 = *(const bf16x8*)(qb + 32);
    }

    f32x4 accO[2][4];
    float mrun[2][4], lrun[2][4];
#pragma unroll
    for (int t = 0; t < 2; ++t) {
#pragma unroll
        for (int dt = 0; dt < 4; ++dt) accO[t][dt] = (f32x4)0.f;
#pragma unroll
        for (int r = 0; r < 4; ++r) { mrun[t][r] = -__builtin_inff(); lrun[t][r] = 0.f; }
    }

    bf16x8 kb[8];  // K tile: 64 kv rows (4 c-subtiles x 2 k-halves)
    auto loadK = [&](int kv) {
#pragma unroll
        for (int c = 0; c < 4; ++c) {
            const unsigned short* kp = Kp + (size_t)(kv + c * 16 + lr) * 64 + lg * 8;
            kb[c * 2] = *(const bf16x8*)kp;
            kb[c * 2 + 1] = *(const bf16x8*)(kp + 32);
        }
    };

    auto qkt = [&](const bf16x8& a0, const bf16x8& a1, f32x4* s) {
        __builtin_amdgcn_s_setprio(1);
#pragma unroll
        for (int c = 0; c < 4; ++c) {
            f32x4 v = (f32x4)0.f;
            v = __builtin_amdgcn_mfma_f32_16x16x32_bf16(a0, kb[c * 2], v, 0, 0, 0);
            v = __builtin_amdgcn_mfma_f32_16x16x32_bf16(a1, kb[c * 2 + 1], v, 0, 0, 0);
            s[c] = v;
        }
        __builtin_amdgcn_s_setprio(0);
    };

    auto maskf = [&](f32x4* s, int q0t, int kv0) {
        if (causal && kv0 + 63 > q0t) {
#pragma unroll
            for (int c = 0; c < 4; ++c) {
                const int col = kv0 + c * 16 + lr;
#pragma unroll
                for (int r = 0; r < 4; ++r)
                    if (col > q0t + lg * 4 + r) s[c][r] = -__builtin_inff();
            }
        }
    };

    // online softmax with defer-max; writes P rows [t*16, t*16+16)
    auto softmax_p = [&](int t, f32x4* s) {
        float pm[4];
        bool sk = true;
#pragma unroll
        for (int r = 0; r < 4; ++r) {
            float tm = fmaxf(fmaxf(s[0][r], s[1][r]), fmaxf(s[2][r], s[3][r]));
            tm = fmaxf(tm, __shfl_xor(tm, 1));
            tm = fmaxf(tm, __shfl_xor(tm, 2));
            tm = fmaxf(tm, __shfl_xor(tm, 4));
            tm = fmaxf(tm, __shfl_xor(tm, 8));
            pm[r] = tm;
            sk = sk && (tm <= mrun[t][r] + THR);
        }
        if (!__all(sk)) {
#pragma unroll
            for (int r = 0; r < 4; ++r) {
                const float mnew = fmaxf(mrun[t][r], pm[r]);
                const float corr = exp2f(mrun[t][r] - mnew);
                mrun[t][r] = mnew;
                lrun[t][r] *= corr;
#pragma unroll
                for (int dt = 0; dt < 4; ++dt) accO[t][dt][r] *= corr;
            }
        }
#pragma unroll
        for (int r = 0; r < 4; ++r) {
            float rs = 0.f;
#pragma unroll
            for (int c = 0; c < 4; ++c) {
                const float p = exp2f(s[c][r] - mrun[t][r]);
                P[wv][(t * 16 + lg * 4 + r) * PS + c * 16 + lr] = f2bf(p);
                rs += p;
            }
            rs += __shfl_xor(rs, 1);
            rs += __shfl_xor(rs, 2);
            rs += __shfl_xor(rs, 4);
            rs += __shfl_xor(rs, 8);
            lrun[t][r] += rs;
        }
    };

    loadK(0);
    for (int kv0 = 0; kv0 < endB; kv0 += 64) {
        const bool actA = (kv0 < endA);
        // all 8 V loads issued at iter top: max outstanding misses, consumed
        // ~500cy later in PV
        bf16x8 vA[4], vB[4];
#pragma unroll
        for (int i = 0; i < 4; ++i) {
            const int dt = i >> 1, h = i & 1;
            vA[i] = *(const bf16x8*)(Vp + (size_t)(dt * 16 + lr) * 2048 + kv0 + h * 32 + lg * 8);
        }
#pragma unroll
        for (int i = 0; i < 4; ++i) {
            const int dt = 2 + (i >> 1), h = i & 1;
            vB[i] = *(const bf16x8*)(Vp + (size_t)(dt * 16 + lr) * 2048 + kv0 + h * 32 + lg * 8);
        }
        f32x4 s[4];
        if (actA) {
            qkt(aA0, aA1, s);
            maskf(s, q0A, kv0);
            softmax_p(0, s);
        }
        qkt(aB0, aB1, s);
        if (kv0 + 64 < endB) loadK(kv0 + 64);  // kb free after last QK^T issue
        maskf(s, q0B, kv0);
        softmax_p(1, s);
        bf16x8 paA0, paA1, paB0, paB1;
        if (actA) {
            paA0 = *(const bf16x8*)&P[wv][lr * PS + lg * 8];
            paA1 = *(const bf16x8*)&P[wv][lr * PS + 32 + lg * 8];
        }
        paB0 = *(const bf16x8*)&P[wv][(16 + lr) * PS + lg * 8];
        paB1 = *(const bf16x8*)&P[wv][(16 + lr) * PS + 32 + lg * 8];
        __builtin_amdgcn_s_setprio(1);
#pragma unroll
        for (int dt = 0; dt < 2; ++dt) {
            if (actA) {
                accO[0][dt] = __builtin_amdgcn_mfma_f32_16x16x32_bf16(paA0, vA[dt * 2], accO[0][dt], 0, 0, 0);
                accO[0][dt] = __builtin_amdgcn_mfma_f32_16x16x32_bf16(paA1, vA[dt * 2 + 1], accO[0][dt], 0, 0, 0);
            }
            accO[1][dt] = __builtin_amdgcn_mfma_f32_16x16x32_bf16(paB0, vA[dt * 2], accO[1][dt], 0, 0, 0);
            accO[1][dt] = __builtin_amdgcn_mfma_f32_16x16x32_bf16(paB1, vA[dt * 2 + 1], accO[1][dt], 0, 0, 0);
        }
#pragma unroll
        for (int dt = 0; dt < 2; ++dt) {
            if (actA) {
                accO[0][2 + dt] = __builtin_amdgcn_mfma_f32_16x16x32_bf16(paA0, vB[dt * 2], accO[0][2 + dt], 0, 0, 0);
                accO[0][2 + dt] = __builtin_amdgcn_mfma_f32_16x16x32_bf16(paA1, vB[dt * 2 + 1], accO[0][2 + dt], 0, 0, 0);
            }
            accO[1][2 + dt] = __builtin_amdgcn_mfma_f32_16x16x32_bf16(paB0, vB[dt * 2], accO[1][2 + dt], 0, 0, 0);
            accO[1][2 + dt] = __builtin_amdgcn_mfma_f32_16x16x32_bf16(paB1, vB[dt * 2 + 1], accO[1][2 + dt], 0, 0, 0);
        }
        __builtin_amdgcn_s_setprio(0);
    }

    // epilogue
    const int b = bh >> 4, h = bh & 15;
#pragma unroll
    for (int t = 0; t < 2; ++t) {
        const int q0t = t ? q0B : q0A;
#pragma unroll
        for (int r = 0; r < 4; ++r) {
            const int q = q0t + lg * 4 + r;
            const float inv = 1.0f / lrun[t][r];
            const size_t base = ((size_t)(b * 2048 + q)) * 1024 + h * 64;
#pragma unroll
            for (int dt = 0; dt < 4; ++dt)
                O[base + dt * 16 + lr] = f2bf(accO[t][dt][r] * inv);
        }
    }
}

extern "C" void kernel_launch(void* const* d_in, const int* in_sizes, int n_in,
                              void* d_out, int out_size, void* d_ws, size_t ws_size,
                              hipStream_t stream) {
    const float* x = (const float*)d_in[0];
    const float* Wqkv = (const float*)d_in[1];
    const float* bqkv = (const float*)d_in[2];
    const float* Wout = (const float*)d_in[3];
    const float* bout = (const float*)d_in[4];
    const int* causal = (const int*)d_in[5];
    float* out = (float*)d_out;

    char* ws = (char*)d_ws;
    unsigned short* xb  = (unsigned short*)(ws);              // 16.78 MB  x bf16 [8192][1024]
    unsigned short* wqt = (unsigned short*)(ws + 16777216);   // 6.29 MB   Wqkv^T bf16 [3072][1024]
    unsigned short* wot = (unsigned short*)(ws + 23068672);   // 2.10 MB   Wout^T bf16 [1024][1024]
    unsigned short* Qb  = (unsigned short*)(ws + 25165824);   // 16.78 MB  [64][2048][64]
    unsigned short* Kb  = (unsigned short*)(ws + 41943040);   // 16.78 MB
    unsigned short* Vtb = (unsigned short*)(ws + 58720256);   // 16.78 MB  [64][64][2048]
    unsigned short* Ob  = xb;                                 // alias: xb dead after QKV GEMM

    k_cvt_bf16<<<2048, 256, 0, stream>>>(x, xb, (8192 * 1024) / 8);
    k_transcvt<<<(1024 / 32) * (3072 / 32), 256, 0, stream>>>(Wqkv, wqt, 1024, 3072, 32);
    k_transcvt<<<(1024 / 32) * (1024 / 32), 256, 0, stream>>>(Wout, wot, 1024, 1024, 32);
    k_gemm<0><<<64 * 24, 256, 0, stream>>>(xb, wqt, bqkv, Qb, Kb, Vtb, nullptr, 24, 1024, 64 * 24);
    k_attn<<<64 * 16, 256, 0, stream>>>(Qb, Kb, Vtb, Ob, causal);
    k_gemm<1><<<64 * 8, 256, 0, stream>>>(Ob, wot, bout, nullptr, nullptr, nullptr, out, 8, 1024, 64 * 8);
}

// Round 10
// 381.980 us; speedup vs baseline: 1.3812x; 1.0968x over previous
//
#include <hip/hip_runtime.h>
#include <hip/hip_bf16.h>

typedef __attribute__((ext_vector_type(8))) short bf16x8;
typedef __attribute__((ext_vector_type(4))) float f32x4;
typedef __attribute__((ext_vector_type(16))) float f32x16;

#define SCALE_Q 0.18033688011112042f  // (1/sqrt(64)) * log2(e)
#define NEG -1.0e30f
#define THR 8.0f

__device__ __forceinline__ unsigned short f2bf(float x) {
    union { float f; unsigned int u; } v; v.f = x;
    unsigned int u = v.u + 0x7fffu + ((v.u >> 16) & 1u);
    return (unsigned short)(u >> 16);
}

// XCD-aware bijective block remap (requires nwg % 8 == 0).
__device__ __forceinline__ int xcd_swz(int bid, int nwg) {
    return (bid & 7) * (nwg >> 3) + (bid >> 3);
}

// ---------------- convert fp32 -> bf16 (vectorized, grid-stride) ----------------
__global__ __launch_bounds__(256) void k_cvt_bf16(const float* __restrict__ in,
                                                  unsigned short* __restrict__ out, int n8) {
    for (int i = blockIdx.x * blockDim.x + threadIdx.x; i < n8; i += gridDim.x * blockDim.x) {
        const float4* p = (const float4*)(in + (size_t)i * 8);
        float4 a = p[0], b = p[1];
        union { bf16x8 v; unsigned short s[8]; } r;
        r.s[0] = f2bf(a.x); r.s[1] = f2bf(a.y); r.s[2] = f2bf(a.z); r.s[3] = f2bf(a.w);
        r.s[4] = f2bf(b.x); r.s[5] = f2bf(b.y); r.s[6] = f2bf(b.z); r.s[7] = f2bf(b.w);
        *(bf16x8*)(out + (size_t)i * 8) = r.v;
    }
}

// ------------- transpose + convert: W[K][N] fp32 -> Wt[N][K] bf16 -------------
__global__ __launch_bounds__(256) void k_transcvt(const float* __restrict__ W,
                                                  unsigned short* __restrict__ Wt,
                                                  int K, int N, int ktiles) {
    __shared__ unsigned short T[32][33];
    const int bk = blockIdx.x % ktiles;
    const int bn = blockIdx.x / ktiles;
    const int t = threadIdx.x;
    const int r = t >> 3;
    const int c4 = (t & 7) << 2;
    float4 v = *(const float4*)(W + (size_t)(bk * 32 + r) * N + bn * 32 + c4);
    T[c4 + 0][r] = f2bf(v.x); T[c4 + 1][r] = f2bf(v.y);
    T[c4 + 2][r] = f2bf(v.z); T[c4 + 3][r] = f2bf(v.w);
    __syncthreads();
    ushort4 o; o.x = T[r][c4]; o.y = T[r][c4 + 1]; o.z = T[r][c4 + 2]; o.w = T[r][c4 + 3];
    *(ushort4*)(Wt + (size_t)(bn * 32 + r) * K + bk * 32 + c4) = o;
}

// ---------------- bf16 MFMA GEMM, 128x128 tile, BK=32, double-buffered ----------------
#define BM 128
#define BN 128
#define BK 32

template <int EPI>
__global__ __launch_bounds__(256) void k_gemm(
    const unsigned short* __restrict__ A, const unsigned short* __restrict__ Bt,
    const float* __restrict__ bias,
    unsigned short* __restrict__ qo, unsigned short* __restrict__ ko,
    unsigned short* __restrict__ vo, float* __restrict__ fo,
    int ntn, int Kd, int nwg) {
    __shared__ __align__(16) unsigned short As[2][BM * BK];
    __shared__ __align__(16) unsigned short Bs[2][BN * BK];

    const int tid = threadIdx.x, lane = tid & 63, wv = tid >> 6;
    const int lb = xcd_swz(blockIdx.x, nwg);
    const int nt = lb % ntn, mt = lb / ntn;
    const int m0 = mt * BM, n0 = nt * BN;
    const int wr = wv >> 1, wc = wv & 1;
    const int lr = lane & 15, lg = lane >> 4;

    f32x4 acc[4][4];
#pragma unroll
    for (int i = 0; i < 4; ++i)
#pragma unroll
        for (int j = 0; j < 4; ++j) acc[i][j] = (f32x4)0.f;

    const int NT = Kd >> 5;
    const int sr = wv * 16 + (lane >> 2);
    const int sc = (lane & 3) * 8;

    auto stage = [&](int t, int buf) {
        const int k0 = t * BK;
#pragma unroll
        for (int p = 0; p < 2; ++p) {
            const unsigned short* ga = A + (size_t)(m0 + p * 64 + sr) * Kd + k0 + sc;
            __builtin_amdgcn_global_load_lds(
                (const __attribute__((address_space(1))) void*)ga,
                (__attribute__((address_space(3))) void*)&As[buf][(p * 64 + wv * 16) * 32],
                16, 0, 0);
        }
#pragma unroll
        for (int p = 0; p < 2; ++p) {
            const unsigned short* gb = Bt + (size_t)(n0 + p * 64 + sr) * Kd + k0 + sc;
            __builtin_amdgcn_global_load_lds(
                (const __attribute__((address_space(1))) void*)gb,
                (__attribute__((address_space(3))) void*)&Bs[buf][(p * 64 + wv * 16) * 32],
                16, 0, 0);
        }
    };

    stage(0, 0);
    int cur = 0;
    for (int t = 0; t < NT; ++t) {
        __syncthreads();
        if (t + 1 < NT) stage(t + 1, cur ^ 1);
        bf16x8 af[4], bf[4];
#pragma unroll
        for (int i = 0; i < 4; ++i)
            af[i] = *(const bf16x8*)&As[cur][(wr * 64 + i * 16 + lr) * 32 + lg * 8];
#pragma unroll
        for (int j = 0; j < 4; ++j)
            bf[j] = *(const bf16x8*)&Bs[cur][(wc * 64 + j * 16 + lr) * 32 + lg * 8];
#pragma unroll
        for (int i = 0; i < 4; ++i)
#pragma unroll
            for (int j = 0; j < 4; ++j)
                acc[i][j] = __builtin_amdgcn_mfma_f32_16x16x32_bf16(af[i], bf[j], acc[i][j], 0, 0, 0);
        cur ^= 1;
    }

#pragma unroll
    for (int i = 0; i < 4; ++i) {
#pragma unroll
        for (int j = 0; j < 4; ++j) {
            const int colg = n0 + wc * 64 + j * 16 + lr;
            const float bv = bias[colg];
#pragma unroll
            for (int r = 0; r < 4; ++r) {
                const int rowg = m0 + wr * 64 + i * 16 + lg * 4 + r;
                const float val = acc[i][j][r] + bv;
                if constexpr (EPI == 0) {
                    const int part = colg >> 10, d = colg & 1023;
                    const int h = d >> 6, hd = d & 63;
                    const int b = rowg >> 11, s = rowg & 2047;
                    const int bh = b * 16 + h;
                    if (part == 0)
                        qo[((size_t)(bh * 2048 + s)) * 64 + hd] = f2bf(val * SCALE_Q);
                    else if (part == 1)
                        ko[((size_t)(bh * 2048 + s)) * 64 + hd] = f2bf(val);
                    else
                        vo[((size_t)(bh * 64 + hd)) * 2048 + s] = f2bf(val);
                } else {
                    fo[(size_t)rowg * (ntn * 128) + colg] = val;
                }
            }
        }
    }
}

// ---------------- flash attention v6: swapped QK^T, shuffle-free P pack ----------------
// S = mfma32x32x16(A=K, B=Q): C[k][q] col=lane&31=q, row k=(ri&3)+8*(ri>>2)+4*hi.
// Lane holds 32 k-scores of one q-row in regs. Row reduce: in-lane + ONE
// __shfl_xor(.,32) (unambiguous). P pack: A/B MFMA slot semantics are symmetric,
// so ANY kappa(hi,j) map works if BOTH pa and V use it. Natural in-lane map:
//   kappa = G*16 + 4*hi + (j&3) + 8*(j>>2),  G = 2c+gp
// -> pa[G] = 4 sequential v_cvt_pk_bf16_f32 of s[c][8gp..8gp+7] (NO cross-lane),
// -> V loaded as two 8B chunks at s = kv0+G*16+4hi and +8. Zero LDS.
__global__ __launch_bounds__(256, 2) void k_attn(
    const unsigned short* __restrict__ Q, const unsigned short* __restrict__ K,
    const unsigned short* __restrict__ Vt, unsigned short* __restrict__ O,
    const int* __restrict__ causal_p) {
    const int tid = threadIdx.x, lane = tid & 63, wv = tid >> 6;
    const int lb = xcd_swz(blockIdx.x, 512);
    const int bh = lb >> 3;
    const int pi = ((lb & 7) << 2) + wv;  // pair index 0..31
    const int ql = lane & 31;             // q-col in S / d-col in accO
    const int hi = lane >> 5;
    const int causal = *causal_p;

    const int q0A = pi * 32;
    const int q0B = 2048 - 32 - q0A;
    const int endA = causal ? (q0A + 32) : 2048;
    const int endB = causal ? (q0B + 32) : 2048;  // endB >= endA

    const unsigned short* Qp = Q + (size_t)bh * 2048 * 64;
    const unsigned short* Kp = K + (size_t)bh * 2048 * 64;
    const unsigned short* Vp = Vt + (size_t)bh * 64 * 2048;

    // Q as B-operand: lane holds Q[q0t+ql][d0*16 + hi*8 + j]
    bf16x8 qA[4], qB[4];
#pragma unroll
    for (int d0 = 0; d0 < 4; ++d0) {
        qA[d0] = *(const bf16x8*)(Qp + (size_t)(q0A + ql) * 64 + d0 * 16 + hi * 8);
        qB[d0] = *(const bf16x8*)(Qp + (size_t)(q0B + ql) * 64 + d0 * 16 + hi * 8);
    }

    f32x16 accO[2][2];
#pragma unroll
    for (int t = 0; t < 2; ++t)
#pragma unroll
        for (int dh = 0; dh < 2; ++dh)
#pragma unroll
            for (int i = 0; i < 16; ++i) accO[t][dh][i] = 0.f;
    float mA = NEG, lA = 0.f, mB = NEG, lB = 0.f;

    // K as A-operand: kb[c*4+d0] = K[kv + c*32 + ql][d0*16 + hi*8 + j]
    bf16x8 kb[8];
    auto loadK = [&](int kv) {
#pragma unroll
        for (int c = 0; c < 2; ++c)
#pragma unroll
            for (int d0 = 0; d0 < 4; ++d0)
                kb[c * 4 + d0] = *(const bf16x8*)(Kp + (size_t)(kv + c * 32 + ql) * 64 + d0 * 16 + hi * 8);
    };

    auto qkt = [&](const bf16x8* qf, f32x16* s) {
        __builtin_amdgcn_s_setprio(1);
#pragma unroll
        for (int c = 0; c < 2; ++c) {
            f32x16 acc = (f32x16)0.f;
#pragma unroll
            for (int d0 = 0; d0 < 4; ++d0)
                acc = __builtin_amdgcn_mfma_f32_32x32x16_bf16(kb[c * 4 + d0], qf[d0], acc, 0, 0, 0);
            s[c] = acc;
        }
        __builtin_amdgcn_s_setprio(0);
    };

    auto maskf = [&](f32x16* s, int q0t, int kv0) {
#pragma unroll
        for (int c = 0; c < 2; ++c)
#pragma unroll
            for (int ri = 0; ri < 16; ++ri) {
                const int k = kv0 + c * 32 + (ri & 3) + 8 * (ri >> 2) + 4 * hi;
                if (k > q0t + ql) s[c][ri] = NEG;
            }
    };

    // in-register softmax + shuffle-free pack into PV A-frags (kappa map above)
    auto softpack = [&](f32x16* s, float& m, float& lsum, f32x16* aco, bf16x8* pa) {
        float tm = fmaxf(s[0][0], s[0][1]);
#pragma unroll
        for (int i = 2; i < 16; ++i) tm = fmaxf(tm, s[0][i]);
#pragma unroll
        for (int i = 0; i < 16; ++i) tm = fmaxf(tm, s[1][i]);
        tm = fmaxf(tm, __shfl_xor(tm, 32));  // cross-half row combine (certain)
        const bool sk = (tm <= m + THR);
        if (!__all(sk)) {  // rare (defer-max): rescale O by corr[row]
            const float mnew = fmaxf(m, tm);
            const float corr = exp2f(m - mnew);
            m = mnew;
            lsum *= corr;
#pragma unroll
            for (int ri = 0; ri < 16; ++ri) {
                const int rq = (ri & 3) + 8 * (ri >> 2) + 4 * hi;
                const float cr = __shfl(corr, rq);
                aco[0][ri] *= cr;
                aco[1][ri] *= cr;
            }
        }
        float rs = 0.f;
#pragma unroll
        for (int c = 0; c < 2; ++c)
#pragma unroll
            for (int i = 0; i < 16; ++i) {
                const float p = exp2f(s[c][i] - m);
                s[c][i] = p;
                rs += p;
            }
        rs += __shfl_xor(rs, 32);  // cross-half row sum
        lsum += rs;
        // pack: pa[2c+gp] = sequential cvt_pk of s[c][8gp+0..7]  (lo = first src,
        // guide-verified m214). Slot (hi,j) -> kappa = G*16+4hi+(j&3)+8*(j>>2).
#pragma unroll
        for (int c = 0; c < 2; ++c)
#pragma unroll
            for (int gp = 0; gp < 2; ++gp) {
                unsigned int d0w, d1w, d2w, d3w;
                asm("v_cvt_pk_bf16_f32 %0, %1, %2"
                    : "=v"(d0w) : "v"(s[c][8 * gp + 0]), "v"(s[c][8 * gp + 1]));
                asm("v_cvt_pk_bf16_f32 %0, %1, %2"
                    : "=v"(d1w) : "v"(s[c][8 * gp + 2]), "v"(s[c][8 * gp + 3]));
                asm("v_cvt_pk_bf16_f32 %0, %1, %2"
                    : "=v"(d2w) : "v"(s[c][8 * gp + 4]), "v"(s[c][8 * gp + 5]));
                asm("v_cvt_pk_bf16_f32 %0, %1, %2"
                    : "=v"(d3w) : "v"(s[c][8 * gp + 6]), "v"(s[c][8 * gp + 7]));
                union { bf16x8 v; unsigned int d[4]; } u;
                u.d[0] = d0w; u.d[1] = d1w; u.d[2] = d2w; u.d[3] = d3w;
                pa[c * 2 + gp] = u.v;
            }
    };

    loadK(0);
    for (int kv0 = 0; kv0 < endB; kv0 += 64) {
        const bool actA = (kv0 < endA);
        // V as B-operand with the SAME kappa map: slot (hi,j) = V[kv0 + G*16 +
        // 4hi + (j&3) + 8*(j>>2)][d]. Two 8B chunks per frag; issued at iter top.
        bf16x8 vf0[4], vf1[4];
#pragma unroll
        for (int G = 0; G < 4; ++G) {
            union { bf16x8 v; ushort4 h[2]; } u0, u1;
            const unsigned short* v0p = Vp + (size_t)ql * 2048 + kv0 + G * 16 + 4 * hi;
            const unsigned short* v1p = Vp + (size_t)(32 + ql) * 2048 + kv0 + G * 16 + 4 * hi;
            u0.h[0] = *(const ushort4*)(v0p);
            u0.h[1] = *(const ushort4*)(v0p + 8);
            u1.h[0] = *(const ushort4*)(v1p);
            u1.h[1] = *(const ushort4*)(v1p + 8);
            vf0[G] = u0.v; vf1[G] = u1.v;
        }
        f32x16 s[2];
        if (actA) {  // tile A: QK^T -> softmax -> PV
            bf16x8 pa[4];
            qkt(qA, s);
            if (causal && kv0 + 63 > q0A) maskf(s, q0A, kv0);
            softpack(s, mA, lA, accO[0], pa);
            __builtin_amdgcn_s_setprio(1);
#pragma unroll
            for (int G = 0; G < 4; ++G) {
                accO[0][0] = __builtin_amdgcn_mfma_f32_32x32x16_bf16(pa[G], vf0[G], accO[0][0], 0, 0, 0);
                accO[0][1] = __builtin_amdgcn_mfma_f32_32x32x16_bf16(pa[G], vf1[G], accO[0][1], 0, 0, 0);
            }
            __builtin_amdgcn_s_setprio(0);
        }
        {    // tile B
            bf16x8 pa[4];
            qkt(qB, s);
            if (kv0 + 64 < endB) loadK(kv0 + 64);  // kb dead after B's QK^T
            if (causal && kv0 + 63 > q0B) maskf(s, q0B, kv0);
            softpack(s, mB, lB, accO[1], pa);
            __builtin_amdgcn_s_setprio(1);
#pragma unroll
            for (int G = 0; G < 4; ++G) {
                accO[1][0] = __builtin_amdgcn_mfma_f32_32x32x16_bf16(pa[G], vf0[G], accO[1][0], 0, 0, 0);
                accO[1][1] = __builtin_amdgcn_mfma_f32_32x32x16_bf16(pa[G], vf1[G], accO[1][1], 0, 0, 0);
            }
            __builtin_amdgcn_s_setprio(0);
        }
    }

    // epilogue: accO col=ql=d, row q=(ri&3)+8*(ri>>2)+4*hi; 1/l fetched per row.
    const int b = bh >> 4, h = bh & 15;
    const float invA = 1.0f / lA;
    const float invB = 1.0f / lB;
#pragma unroll
    for (int ri = 0; ri < 16; ++ri) {
        const int rq = (ri & 3) + 8 * (ri >> 2) + 4 * hi;
        const float ivA = __shfl(invA, rq);
        const float ivB = __shfl(invB, rq);
        {
            const size_t base = ((size_t)(b * 2048 + q0A + rq)) * 1024 + h * 64;
            O[base + ql] = f2bf(accO[0][0][ri] * ivA);
            O[base + 32 + ql] = f2bf(accO[0][1][ri] * ivA);
        }
        {
            const size_t base = ((size_t)(b * 2048 + q0B + rq)) * 1024 + h * 64;
            O[base + ql] = f2bf(accO[1][0][ri] * ivB);
            O[base + 32 + ql] = f2bf(accO[1][1][ri] * ivB);
        }
    }
}

extern "C" void kernel_launch(void* const* d_in, const int* in_sizes, int n_in,
                              void* d_out, int out_size, void* d_ws, size_t ws_size,
                              hipStream_t stream) {
    const float* x = (const float*)d_in[0];
    const float* Wqkv = (const float*)d_in[1];
    const float* bqkv = (const float*)d_in[2];
    const float* Wout = (const float*)d_in[3];
    const float* bout = (const float*)d_in[4];
    const int* causal = (const int*)d_in[5];
    float* out = (float*)d_out;

    char* ws = (char*)d_ws;
    unsigned short* xb  = (unsigned short*)(ws);              // 16.78 MB  x bf16 [8192][1024]
    unsigned short* wqt = (unsigned short*)(ws + 16777216);   // 6.29 MB   Wqkv^T bf16 [3072][1024]
    unsigned short* wot = (unsigned short*)(ws + 23068672);   // 2.10 MB   Wout^T bf16 [1024][1024]
    unsigned short* Qb  = (unsigned short*)(ws + 25165824);   // 16.78 MB  [64][2048][64]
    unsigned short* Kb  = (unsigned short*)(ws + 41943040);   // 16.78 MB
    unsigned short* Vtb = (unsigned short*)(ws + 58720256);   // 16.78 MB  [64][64][2048]
    unsigned short* Ob  = xb;                                 // alias: xb dead after QKV GEMM

    k_cvt_bf16<<<2048, 256, 0, stream>>>(x, xb, (8192 * 1024) / 8);
    k_transcvt<<<(1024 / 32) * (3072 / 32), 256, 0, stream>>>(Wqkv, wqt, 1024, 3072, 32);
    k_transcvt<<<(1024 / 32) * (1024 / 32), 256, 0, stream>>>(Wout, wot, 1024, 1024, 32);
    k_gemm<0><<<64 * 24, 256, 0, stream>>>(xb, wqt, bqkv, Qb, Kb, Vtb, nullptr, 24, 1024, 64 * 24);
    k_attn<<<512, 256, 0, stream>>>(Qb, Kb, Vtb, Ob, causal);
    k_gemm<1><<<64 * 8, 256, 0, stream>>>(Ob, wot, bout, nullptr, nullptr, nullptr, out, 8, 1024, 64 * 8);
}